// Round 6
// baseline (23.381 us; speedup 1.0000x reference)
//
#include <hip/hip_runtime.h>
#include <math.h>

// Problem constants (match reference)
constexpr int S = 4096;
constexpr int THREADS = 128;                   // 2 waves/block
constexpr int PER_THREAD = S / (THREADS * 4);  // 8 int4 loads per thread (deep MLP)

typedef int iv4 __attribute__((ext_vector_type(4)));  // native vector: OK for nontemporal builtin

__global__ __launch_bounds__(THREADS)
void cca_kernel(const float* __restrict__ drowsy,
                const int* __restrict__ gest,
                float* __restrict__ out) {
    const int row = blockIdx.x;
    const int t = threadIdx.x;
    const iv4* g4 = reinterpret_cast<const iv4*>(gest + (size_t)row * S);

    int cnt = 0;   // number of ones in row
    int last = -1; // last index where g == 1

    #pragma unroll
    for (int k = 0; k < PER_THREAD; ++k) {
        const int idx4 = k * THREADS + t;   // int4 index within row (coalesced)
        // Nontemporal streaming read: no cache allocation (nt flag)
        const iv4 v = __builtin_nontemporal_load(&g4[idx4]);
        const int base = idx4 * 4;
        cnt += v.x + v.y + v.z + v.w;
        // values are 0/1; ascending order, so later assignments are larger idx
        if (v.x) last = base + 0;
        if (v.y) last = base + 1;
        if (v.z) last = base + 2;
        if (v.w) last = base + 3;
    }

    // wave-level reduction (64 lanes)
    #pragma unroll
    for (int m = 1; m < 64; m <<= 1) {
        cnt += __shfl_xor(cnt, m, 64);
        last = max(last, __shfl_xor(last, m, 64));
    }

    __shared__ int s_cnt[THREADS / 64];
    __shared__ int s_last[THREADS / 64];
    const int wave = t >> 6;
    if ((t & 63) == 0) { s_cnt[wave] = cnt; s_last[wave] = last; }
    __syncthreads();

    if (t == 0) {
        int C = 0, L = -1;
        #pragma unroll
        for (int w = 0; w < THREADS / 64; ++w) {
            C += s_cnt[w];
            L = max(L, s_last[w]);
        }
        const int pos = (L >= 0) ? L : 0;   // argmax of all-zero row is 0

        // max_eye = C; max_att = S-1-pos (or -inf if pos == S-1)
        float adjustment = 0.0f;
        if (C >= 40 && pos <= S - 1 - 40) { // max_eye>=40 && max_att>=40 (finite)
            const float max_att = (float)(S - 1 - pos);
            const float excess = max_att - 40.0f;            // >= 0 here
            adjustment = 0.05f * (1.0f - expf(-excess * (3.0f / 160.0f)));
        }
        float r = drowsy[row] * (1.0f - adjustment);
        r = fminf(fmaxf(r, 0.01f), 1.0f);
        out[row] = r;
    }
}

extern "C" void kernel_launch(void* const* d_in, const int* in_sizes, int n_in,
                              void* d_out, int out_size, void* d_ws, size_t ws_size,
                              hipStream_t stream) {
    const float* drowsy = (const float*)d_in[0]; // [B,1] float32
    const int* gest = (const int*)d_in[1];       // [B,S,1] int32
    float* out = (float*)d_out;                  // [B,1] float32
    const int B = in_sizes[0];                   // 8192

    cca_kernel<<<B, THREADS, 0, stream>>>(drowsy, gest, out);
}

// Round 7
// 22.779 us; speedup vs baseline: 1.0264x; 1.0264x over previous
//
#include <hip/hip_runtime.h>
#include <math.h>

// Problem constants (match reference)
constexpr int S = 4096;
constexpr int THREADS = 256;
constexpr int PER_THREAD = S / (THREADS * 4); // 4 int4 loads per thread

typedef int iv4 __attribute__((ext_vector_type(4)));  // native vector: OK for nontemporal builtin

// Best measured config (R4): block-per-row, 256 thr, nt loads -> 22.91 us (~5.9 TB/s read).
// R5 (128 thr / 8 int4) was +2%; R1 (wave-per-row) +3%; R2 (2 rows/wave) +12%.
__global__ __launch_bounds__(THREADS)
void cca_kernel(const float* __restrict__ drowsy,
                const int* __restrict__ gest,
                float* __restrict__ out) {
    const int row = blockIdx.x;
    const int t = threadIdx.x;
    const iv4* g4 = reinterpret_cast<const iv4*>(gest + (size_t)row * S);

    int cnt = 0;   // number of ones in row      -> max_eye
    int last = -1; // last index where g == 1    -> pos (first argmax of eye_streaks)

    #pragma unroll
    for (int k = 0; k < PER_THREAD; ++k) {
        const int idx4 = k * THREADS + t;   // int4 index within row (coalesced)
        // Nontemporal streaming read: skip L2/L3 allocation (nt flag) — input has zero reuse
        const iv4 v = __builtin_nontemporal_load(&g4[idx4]);
        const int base = idx4 * 4;
        cnt += v.x + v.y + v.z + v.w;
        // values are 0/1; ascending order, so later assignments are larger idx
        if (v.x) last = base + 0;
        if (v.y) last = base + 1;
        if (v.z) last = base + 2;
        if (v.w) last = base + 3;
    }

    // wave-level reduction (64 lanes)
    #pragma unroll
    for (int m = 1; m < 64; m <<= 1) {
        cnt += __shfl_xor(cnt, m, 64);
        last = max(last, __shfl_xor(last, m, 64));
    }

    __shared__ int s_cnt[THREADS / 64];
    __shared__ int s_last[THREADS / 64];
    const int wave = t >> 6;
    if ((t & 63) == 0) { s_cnt[wave] = cnt; s_last[wave] = last; }
    __syncthreads();

    if (t == 0) {
        int C = 0, L = -1;
        #pragma unroll
        for (int w = 0; w < THREADS / 64; ++w) {
            C += s_cnt[w];
            L = max(L, s_last[w]);
        }
        const int pos = (L >= 0) ? L : 0;   // argmax of all-zero row is 0

        // max_eye = C; max_att = S-1-pos (or -inf if pos == S-1)
        float adjustment = 0.0f;
        if (C >= 40 && pos <= S - 1 - 40) { // max_eye>=40 && max_att>=40 (finite)
            const float max_att = (float)(S - 1 - pos);
            const float excess = max_att - 40.0f;            // >= 0 here
            adjustment = 0.05f * (1.0f - expf(-excess * (3.0f / 160.0f)));
        }
        float r = drowsy[row] * (1.0f - adjustment);
        r = fminf(fmaxf(r, 0.01f), 1.0f);
        out[row] = r;
    }
}

extern "C" void kernel_launch(void* const* d_in, const int* in_sizes, int n_in,
                              void* d_out, int out_size, void* d_ws, size_t ws_size,
                              hipStream_t stream) {
    const float* drowsy = (const float*)d_in[0]; // [B,1] float32
    const int* gest = (const int*)d_in[1];       // [B,S,1] int32
    float* out = (float*)d_out;                  // [B,1] float32
    const int B = in_sizes[0];                   // 8192

    cca_kernel<<<B, THREADS, 0, stream>>>(drowsy, gest, out);
}